// Round 3
// baseline (137.660 us; speedup 1.0000x reference)
//
#include <hip/hip_runtime.h>

// Problem constants
#define BB 32
#define NN 10
#define IN_DIM 65536
#define HEADS 8
#define DD 8
#define ROWS (BB*NN)            // 320 "bn" rows
#define K4 (IN_DIM/4)           // 16384 float4 per row
#define SPLITS 16
#define KSPLIT (K4/SPLITS)      // 1024 float4 per block
#define KWAVE (KSPLIT/4)        // 256 float4 per wave
#define RGROUP 4
#define NGROUPS (ROWS/RGROUP)   // 80
#define GEMV_BLOCKS (NGROUPS*SPLITS)  // 1280

// ---------------------------------------------------------------------------
// Kernel 1: Wh[h][k] = sum_{d=0..7} W[h*8+d][k]; also zeroes the block counter.
// ---------------------------------------------------------------------------
__global__ __launch_bounds__(256) void wreduce_kernel(const float* __restrict__ W,
                                                      float* __restrict__ Wh,
                                                      unsigned* __restrict__ counter) {
    if (blockIdx.x == 0 && threadIdx.x == 0) *counter = 0u;
    int idx = blockIdx.x * blockDim.x + threadIdx.x;   // 0 .. 8*16384-1
    int h  = idx >> 14;
    int k4 = idx & 16383;
    const float4* W4 = (const float4*)W;
    float4 s = make_float4(0.f, 0.f, 0.f, 0.f);
#pragma unroll
    for (int d = 0; d < DD; ++d) {
        float4 v = W4[(h * DD + d) * K4 + k4];
        s.x += v.x; s.y += v.y; s.z += v.z; s.w += v.w;
    }
    ((float4*)Wh)[h * K4 + k4] = s;
}

// ---------------------------------------------------------------------------
// Kernel 2 (fused): partial GEMV + last-block finalize.
// Block (g, split): rows g*4..g*4+3, k-chunk split. Each wave owns ALL 8 heads
// and a disjoint quarter of the k-chunk -> x and Wh each instruction-loaded
// exactly once chip-wide. Partials combined across waves in LDS, written to
// partials[split][bn][h]. Last block (device-scope counter) sums splits,
// multiplies by adj, applies ReLU, writes out.
// ---------------------------------------------------------------------------
__global__ __launch_bounds__(256) void gemv_fused_kernel(const float* __restrict__ x,
                                                         const float* __restrict__ Wh,
                                                         const float* __restrict__ adj,
                                                         float* __restrict__ partials,
                                                         unsigned* __restrict__ counter,
                                                         float* __restrict__ out) {
    const int g     = blockIdx.x % NGROUPS;
    const int split = blockIdx.x / NGROUPS;
    const int t     = threadIdx.x;
    const int lane  = t & 63;
    const int wave  = t >> 6;      // 0..3

    __shared__ float red[4][RGROUP * HEADS];
    __shared__ float ssum[ROWS * HEADS];     // 2560 floats, used by last block
    __shared__ unsigned s_last;

    const float4* x4  = (const float4*)x;
    const float4* Wh4 = (const float4*)Wh;

    float acc[RGROUP][HEADS];
#pragma unroll
    for (int r = 0; r < RGROUP; ++r)
#pragma unroll
        for (int h = 0; h < HEADS; ++h) acc[r][h] = 0.f;

    const int kbase = split * KSPLIT + wave * KWAVE + lane;

#pragma unroll 2
    for (int i = 0; i < KWAVE / 64; ++i) {   // 4 iterations
        const int k4 = kbase + i * 64;
        float4 wv[HEADS];
#pragma unroll
        for (int h = 0; h < HEADS; ++h) wv[h] = Wh4[h * K4 + k4];
#pragma unroll
        for (int r = 0; r < RGROUP; ++r) {
            float4 xv = x4[(size_t)(g * RGROUP + r) * K4 + k4];
#pragma unroll
            for (int h = 0; h < HEADS; ++h) {
                acc[r][h] += xv.x * wv[h].x + xv.y * wv[h].y
                           + xv.z * wv[h].z + xv.w * wv[h].w;
            }
        }
    }

    // reduce each accumulator across the 64 lanes of the wave
#pragma unroll
    for (int r = 0; r < RGROUP; ++r) {
#pragma unroll
        for (int h = 0; h < HEADS; ++h) {
            float v = acc[r][h];
#pragma unroll
            for (int off = 32; off > 0; off >>= 1) v += __shfl_down(v, off);
            acc[r][h] = v;
        }
    }
    if (lane == 0) {
#pragma unroll
        for (int r = 0; r < RGROUP; ++r)
#pragma unroll
            for (int h = 0; h < HEADS; ++h)
                red[wave][r * HEADS + h] = acc[r][h];
    }
    __syncthreads();
    if (t < RGROUP * HEADS) {
        float v = red[0][t] + red[1][t] + red[2][t] + red[3][t];
        const int bn = g * RGROUP + (t >> 3);
        partials[(size_t)split * (ROWS * HEADS) + bn * HEADS + (t & 7)] = v;
    }

    // ---- last-block finalize ----
    __syncthreads();
    __threadfence();   // make this block's partials visible device-wide
    if (t == 0) {
        unsigned old = __hip_atomic_fetch_add(counter, 1u, __ATOMIC_ACQ_REL,
                                              __HIP_MEMORY_SCOPE_AGENT);
        s_last = (old == (unsigned)(GEMV_BLOCKS - 1)) ? 1u : 0u;
    }
    __syncthreads();
    if (s_last) {
        __threadfence();   // acquire: invalidate stale cache lines
        for (int idx = t; idx < ROWS * HEADS; idx += 256) {
            float v = 0.f;
#pragma unroll
            for (int sp = 0; sp < SPLITS; ++sp)
                v += partials[(size_t)sp * (ROWS * HEADS) + idx];
            ssum[idx] = v;
        }
        __syncthreads();
        for (int idx = t; idx < ROWS * HEADS * NN; idx += 256) {  // 25600 outputs
            const int bn  = idx / (HEADS * NN);
            const int rem = idx % (HEADS * NN);
            const int h = rem / NN;
            const int m = rem % NN;
            float v = ssum[bn * HEADS + h] * adj[bn * NN + m];
            out[idx] = v > 0.f ? v : 0.f;
        }
    }
}

extern "C" void kernel_launch(void* const* d_in, const int* in_sizes, int n_in,
                              void* d_out, int out_size, void* d_ws, size_t ws_size,
                              hipStream_t stream) {
    const float* x   = (const float*)d_in[0];   // (32,10,65536)
    const float* adj = (const float*)d_in[1];   // (32,10,10)
    const float* W   = (const float*)d_in[2];   // (64,65536)
    float* out = (float*)d_out;                 // (32,10,80) = 25600 floats

    // workspace: Wh (8*65536 f) | partials (16*2560 f) | counter (1 u32)
    float* Wh       = (float*)d_ws;
    float* partials = Wh + (size_t)HEADS * IN_DIM;
    unsigned* counter = (unsigned*)(partials + (size_t)SPLITS * ROWS * HEADS);

    wreduce_kernel<<<(HEADS * K4) / 256, 256, 0, stream>>>(W, Wh, counter);
    gemv_fused_kernel<<<GEMV_BLOCKS, 256, 0, stream>>>(x, Wh, adj, partials, counter, out);
}

// Round 4
// 30.266 us; speedup vs baseline: 4.5483x; 4.5483x over previous
//
#include <hip/hip_runtime.h>

// Problem constants
#define BB 32
#define NN 10
#define IN_DIM 65536
#define HEADS 8
#define DD 8
#define ROWS (BB*NN)            // 320 "bn" rows
#define K4 (IN_DIM/4)           // 16384 float4 per row
#define SPLITS 16
#define KSPLIT (K4/SPLITS)      // 1024 float4 per block
#define KHALF (KSPLIT/2)        // 512 float4 per k-half
#define RGROUP 4
#define NGROUPS (ROWS/RGROUP)   // 80

// ---------------------------------------------------------------------------
// Kernel 1: Wh[h][k] = sum_{d=0..7} W[h*8+d][k]   (W is 64 x 65536 row-major)
// ---------------------------------------------------------------------------
__global__ __launch_bounds__(256) void wreduce_kernel(const float* __restrict__ W,
                                                      float* __restrict__ Wh) {
    int idx = blockIdx.x * blockDim.x + threadIdx.x;   // 0 .. 8*16384-1
    int h  = idx >> 14;
    int k4 = idx & 16383;
    const float4* W4 = (const float4*)W;
    float4 s = make_float4(0.f, 0.f, 0.f, 0.f);
#pragma unroll
    for (int d = 0; d < DD; ++d) {
        float4 v = W4[(h * DD + d) * K4 + k4];
        s.x += v.x; s.y += v.y; s.z += v.z; s.w += v.w;
    }
    ((float4*)Wh)[h * K4 + k4] = s;
}

// ---------------------------------------------------------------------------
// Kernel 2: partial GEMV. s[bn][h] = x[bn][:] . Wh[h][:]
// grid = NGROUPS * SPLITS = 1280 blocks, 256 threads.
// Block (g, split): rows g*4..g*4+3, k-chunk [split*KSPLIT, +KSPLIT).
// Wave w: khalf = w>>1 (which 512-float4 half), hgroup = w&1 (heads 4hg..4hg+3).
// => each x float4 is instruction-loaded by exactly 2 waves (L1-served),
//    each wave carries only 16 accumulators + 4 Wh fragments (no spill).
// Writes partials[split][bn][h]  (16 x 320 x 8 floats)
// ---------------------------------------------------------------------------
__global__ __launch_bounds__(256) void gemv_part_kernel(const float* __restrict__ x,
                                                        const float* __restrict__ Wh,
                                                        float* __restrict__ partials) {
    const int g     = blockIdx.x % NGROUPS;
    const int split = blockIdx.x / NGROUPS;
    const int t     = threadIdx.x;
    const int lane  = t & 63;
    const int wave  = t >> 6;      // 0..3
    const int hg    = wave & 1;    // head group: heads hg*4 .. hg*4+3
    const int kh    = wave >> 1;   // k-half

    const float4* x4  = (const float4*)x;
    const float4* Wh4 = (const float4*)Wh;

    float acc[RGROUP][4];
#pragma unroll
    for (int r = 0; r < RGROUP; ++r)
#pragma unroll
        for (int h = 0; h < 4; ++h) acc[r][h] = 0.f;

    const int kbase = split * KSPLIT + kh * KHALF + lane;

#pragma unroll 2
    for (int i = 0; i < KHALF / 64; ++i) {   // 8 iterations
        const int k4 = kbase + i * 64;
        float4 wv[4];
#pragma unroll
        for (int h = 0; h < 4; ++h) wv[h] = Wh4[(size_t)(hg * 4 + h) * K4 + k4];
#pragma unroll
        for (int r = 0; r < RGROUP; ++r) {
            float4 xv = x4[(size_t)(g * RGROUP + r) * K4 + k4];
#pragma unroll
            for (int h = 0; h < 4; ++h) {
                acc[r][h] += xv.x * wv[h].x + xv.y * wv[h].y
                           + xv.z * wv[h].z + xv.w * wv[h].w;
            }
        }
    }

    // reduce each of the 16 accumulators across the 64 lanes
#pragma unroll
    for (int r = 0; r < RGROUP; ++r) {
#pragma unroll
        for (int h = 0; h < 4; ++h) {
            float v = acc[r][h];
#pragma unroll
            for (int off = 32; off > 0; off >>= 1) v += __shfl_down(v, off);
            acc[r][h] = v;
        }
    }

    __shared__ float red[4][RGROUP * 4];
    if (lane == 0) {
#pragma unroll
        for (int r = 0; r < RGROUP; ++r)
#pragma unroll
            for (int h = 0; h < 4; ++h)
                red[wave][r * 4 + h] = acc[r][h];
    }
    __syncthreads();

    // combine the two k-halves; t<32 covers (r 0..3, h 0..7)
    if (t < RGROUP * HEADS) {
        const int r  = t >> 3;
        const int h  = t & 7;
        const int hgr = h >> 2;
        const int hh  = h & 3;
        float v = red[hgr][r * 4 + hh] + red[hgr + 2][r * 4 + hh];
        const int bn = g * RGROUP + r;
        partials[(size_t)split * (ROWS * HEADS) + bn * HEADS + h] = v;
    }
}

// ---------------------------------------------------------------------------
// Kernel 3: out[bn][h*10+m] = relu( (sum_s partials[s][bn][h]) * adj[bn][m] )
// ---------------------------------------------------------------------------
__global__ __launch_bounds__(256) void finalize_kernel(const float* __restrict__ partials,
                                                       const float* __restrict__ adj,
                                                       float* __restrict__ out,
                                                       int out_size) {
    int idx = blockIdx.x * blockDim.x + threadIdx.x;
    if (idx >= out_size) return;
    int bn  = idx / (HEADS * NN);
    int rem = idx % (HEADS * NN);
    int h = rem / NN;
    int m = rem % NN;
    float s = 0.f;
#pragma unroll
    for (int sp = 0; sp < SPLITS; ++sp)
        s += partials[(size_t)sp * (ROWS * HEADS) + bn * HEADS + h];
    float v = s * adj[bn * NN + m];
    out[idx] = v > 0.f ? v : 0.f;
}

extern "C" void kernel_launch(void* const* d_in, const int* in_sizes, int n_in,
                              void* d_out, int out_size, void* d_ws, size_t ws_size,
                              hipStream_t stream) {
    const float* x   = (const float*)d_in[0];   // (32,10,65536)
    const float* adj = (const float*)d_in[1];   // (32,10,10)
    const float* W   = (const float*)d_in[2];   // (64,65536)
    float* out = (float*)d_out;                 // (32,10,80) = 25600 floats

    // workspace layout: Wh (8*65536 f = 2 MiB) | partials (16*2560 f)
    float* Wh       = (float*)d_ws;
    float* partials = Wh + (size_t)HEADS * IN_DIM;

    // K1: reduce W -> Wh. 8*16384 = 131072 threads.
    wreduce_kernel<<<(HEADS * K4) / 256, 256, 0, stream>>>(W, Wh);

    // K2: partial GEMV. 80 groups x 16 splits = 1280 blocks.
    gemv_part_kernel<<<NGROUPS * SPLITS, 256, 0, stream>>>(x, Wh, partials);

    // K3: finalize. 25600 outputs.
    finalize_kernel<<<(out_size + 255) / 256, 256, 0, stream>>>(partials, adj, out, out_size);
}